// Round 8
// baseline (282.927 us; speedup 1.0000x reference)
//
#include <hip/hip_runtime.h>
#include <hip/hip_bf16.h>

typedef __hip_bfloat16 bf16;
typedef __attribute__((ext_vector_type(8))) short s16x8;
typedef __attribute__((ext_vector_type(4))) float f32x4;

constexpr int cN = 128, cC = 64, cT = 64, cV = 25, cK = 3, cMID = 64, cKM = 192, cTV = 1600;
constexpr float cEPS = 1e-5f;

// All intermediates in BSS: zero d_ws dependency; loader zero-inits once.
__device__ float g_tmp[cN * cC * cV];
__device__ float g_x1 [cN * cKM * cV];
__device__ float g_x2 [cN * cKM * cV];
__device__ float g_ada[cN * cK * cV * cV];
// pre_x in v-PADDED layout [n][o][t][32]; pads only ever multiply exact-zero B rows.
__device__ ushort g_pre32[(size_t)cN * cKM * cT * 32];     // 100.7 MB
// Z pre-transposed in B-fragment order: [n][k/8][col][8] bf16, 16B per chunk.
// Octets 0..23 = y channels (by gm_y2), 24..31 = x channels (by k_xt).
__device__ ushort g_zt[(size_t)cN * 32 * cTV * 8];         // 104.9 MB
// Folded weights (bn scale/shift + bias absorbed), built by k_fold each call:
__device__ bf16  g_Wpre [cKM * cC];
__device__ float g_bpre [cKM];
__device__ bf16  g_Wcat [cKM * 256];
__device__ float g_cterm[cKM];

__device__ __forceinline__ float b2f(bf16 v){ return __bfloat162float(v); }
__device__ __forceinline__ bf16  f2b(float v){ return __float2bfloat16(v); }
__device__ __forceinline__ ushort f2bu(float v){ return __builtin_bit_cast(ushort, __float2bfloat16(v)); }

// ---------------------------------------------------------------------------
// 0) fold bn into weights/biases, cast weights to bf16.  1 block, 256 thr.
// ---------------------------------------------------------------------------
__global__ void k_fold(const float* __restrict__ Wpre, const float* __restrict__ bpre,
                       const float* __restrict__ bnpre,
                       const float* __restrict__ Wpost, const float* __restrict__ bpost,
                       const float* __restrict__ bnpost,
                       const float* __restrict__ Wdown, const float* __restrict__ bdown,
                       const float* __restrict__ bndown){
  __shared__ float sPre[cKM], sPost[cKM], sDown[cKM];
  int tid = threadIdx.x;
  if (tid < cKM){
    float sp = bnpre[tid] * rsqrtf(bnpre[3*cKM+tid] + cEPS);
    sPre[tid] = sp;
    g_bpre[tid] = bpre[tid]*sp + bnpre[cKM+tid] - bnpre[2*cKM+tid]*sp;
    float sP = bnpost[tid] * rsqrtf(bnpost[3*cKM+tid] + cEPS);
    float sD = bndown[tid] * rsqrtf(bndown[3*cKM+tid] + cEPS);
    sPost[tid] = sP; sDown[tid] = sD;
    g_cterm[tid] = bpost[tid]*sP + bnpost[cKM+tid] - bnpost[2*cKM+tid]*sP
                 + bdown[tid]*sD + bndown[cKM+tid] - bndown[2*cKM+tid]*sD;
  }
  __syncthreads();
  for (int idx = tid; idx < cKM*cC; idx += 256){
    int o = idx >> 6;
    g_Wpre[idx] = f2b(Wpre[idx] * sPre[o]);
  }
  for (int idx = tid; idx < cKM*256; idx += 256){
    int o = idx >> 8, k = idx & 255;
    float w = (k < cKM) ? Wpost[o*cKM + k] * sPost[o]
                        : Wdown[o*cC + (k - cKM)] * sDown[o];
    g_Wcat[idx] = f2b(w);
  }
}

// ---------------------------------------------------------------------------
// 1) g_tmp[n,c,v] = mean_t x[n,c,t,v]
// ---------------------------------------------------------------------------
__global__ void gm_tmp(const float* __restrict__ x){
  int b = blockIdx.x;
  int l = threadIdx.x;
  if (l >= cV) return;
  const float* p = x + (size_t)b * cTV + l;
  float s = 0.f;
  #pragma unroll
  for (int t = 0; t < cT; ++t) s += p[t * cV];
  g_tmp[b * cV + l] = s * (1.f / cT);
}

// ---------------------------------------------------------------------------
// 2) x1/x2 1x1 conv on mean
// ---------------------------------------------------------------------------
__global__ void gm_x1x2(const float* __restrict__ W1, const float* __restrict__ b1,
                        const float* __restrict__ W2, const float* __restrict__ b2){
  __shared__ float tl[cC * cV];
  __shared__ float w1[48 * cC];
  __shared__ float w2[48 * cC];
  int n = blockIdx.x >> 2, og = blockIdx.x & 3;
  int tid = threadIdx.x;
  int obase = og * 48;
  for (int i = tid; i < cC * cV; i += 256) tl[i] = g_tmp[n * cC * cV + i];
  for (int i = tid; i < 48 * cC; i += 256){
    w1[i] = W1[obase * cC + i];
    w2[i] = W2[obase * cC + i];
  }
  __syncthreads();
  for (int idx = tid; idx < 48 * cV; idx += 256){
    int j = idx / cV, v = idx % cV;
    int o = obase + j;
    float s1 = b1[o], s2 = b2[o];
    #pragma unroll
    for (int c = 0; c < cC; ++c){
      float t = tl[c * cV + v];
      s1 += w1[j * cC + c] * t;
      s2 += w2[j * cC + c] * t;
    }
    g_x1[((size_t)n * cKM + o) * cV + v] = s1;
    g_x2[((size_t)n * cKM + o) * cV + v] = s2;
  }
}

// ---------------------------------------------------------------------------
// 3) ada softmax
// ---------------------------------------------------------------------------
__global__ void gm_ada(const float* __restrict__ beta){
  __shared__ float a1[cMID * cV];
  __shared__ float a2[cMID * cV];
  __shared__ float al[cV * cV];
  int b = blockIdx.x; int n = b / cK, k = b % cK;
  int tid = threadIdx.x;
  const float* p1 = g_x1 + ((size_t)n * cKM + k * cMID) * cV;
  const float* p2 = g_x2 + ((size_t)n * cKM + k * cMID) * cV;
  for (int i = tid; i < cMID * cV; i += 128){ a1[i] = p1[i]; a2[i] = p2[i]; }
  __syncthreads();
  for (int idx = tid; idx < cV * cV; idx += 128){
    int v = idx / cV, w = idx % cV;
    float s = 0.f;
    #pragma unroll
    for (int c = 0; c < cMID; ++c) s += a1[c * cV + v] * a2[c * cV + w];
    al[idx] = s;
  }
  __syncthreads();
  float b0 = beta[0];
  if (tid < cV){
    int w = tid;
    float m = -1e30f;
    for (int v = 0; v < cV; ++v) m = fmaxf(m, al[v * cV + w]);
    float s = 0.f;
    for (int v = 0; v < cV; ++v) s += expf(al[v * cV + w] - m);
    float inv = b0 / s;
    for (int v = 0; v < cV; ++v)
      g_ada[(size_t)b * cV * cV + v * cV + w] = expf(al[v * cV + w] - m) * inv;
  }
}

// ---------------------------------------------------------------------------
// 3b) k_xt: x (f32, k-major) -> g_zt octets 24..31 (bf16, B-fragment order).
//     grid = N*7 (col tiles of 256), 256 thr.  Reads coalesced per channel,
//     writes coalesced 16B chunks.
// ---------------------------------------------------------------------------
__global__ __launch_bounds__(256) void k_xt(const float* __restrict__ x){
  int n = blockIdx.x / 7, tile = blockIdx.x % 7;
  int col = tile * 256 + threadIdx.x;
  if (col >= cTV) return;
  const float* xp = x + (size_t)n * cC * cTV + col;
  ushort* zp = g_zt + (((size_t)n * 32 + 24) * cTV + col) * 8;
  #pragma unroll
  for (int oct = 0; oct < 8; ++oct){
    ushort u[8];
    #pragma unroll
    for (int j = 0; j < 8; ++j) u[j] = f2bu(xp[(size_t)(oct * 8 + j) * cTV]);
    *(uint4*)(zp + (size_t)oct * cTV * 8) = *(const uint4*)u;
  }
}

// ---------------------------------------------------------------------------
// 4+6) LDS-FREE streaming MFMA GEMM: C[192 x 64cols] per (n, coltile).
//   A-frags direct from folded-W global (L2-hot); B-frags direct from g_zt.
//   MODE 0: K=64 (x octets 24..31) -> g_pre32 (bf16, relu, padded layout)
//   MODE 1: K=256 (octets 0..31)   -> d_out (f32, relu)
//   No __shared__, no barriers.  XCD-aware block swizzle (nwg=3200, %8==0).
// ---------------------------------------------------------------------------
template<int MODE>
__global__ __launch_bounds__(256) void gm_mm(float* __restrict__ outf){
  constexpr int KTOT = MODE ? 256 : 64;
  int bid = (int)(blockIdx.x & 7) * 400 + ((int)blockIdx.x >> 3);  // XCD swizzle
  int n = bid / 25, tile = bid % 25;
  int colb = tile * 64;
  int tid = threadIdx.x;
  int lane = tid & 63, wv = tid >> 6, g = lane >> 4, l15 = lane & 15;

  const ushort* Wsrc = (const ushort*)(MODE ? g_Wcat : g_Wpre);
  const ushort* zb = g_zt + ((size_t)n * 32 + (MODE ? 0 : 24)) * cTV * 8;
  const float*  cb = MODE ? g_cterm : g_bpre;

  f32x4 acc[3][4];
  #pragma unroll
  for (int a = 0; a < 3; ++a)
    #pragma unroll
    for (int b = 0; b < 4; ++b) acc[a][b] = (f32x4){0.f,0.f,0.f,0.f};

  #pragma unroll 2
  for (int kb = 0; kb < KTOT; kb += 32){
    s16x8 av[3], bv[4];
    #pragma unroll
    for (int mf = 0; mf < 3; ++mf)
      av[mf] = *(const s16x8*)(Wsrc + (48*wv + 16*mf + l15) * KTOT + kb + 8*g);
    int oct = (kb >> 3) + g;
    #pragma unroll
    for (int nf = 0; nf < 4; ++nf)
      bv[nf] = *(const s16x8*)(zb + ((size_t)oct * cTV + colb + 16*nf + l15) * 8);
    #pragma unroll
    for (int mf = 0; mf < 3; ++mf)
      #pragma unroll
      for (int nf = 0; nf < 4; ++nf)
        acc[mf][nf] = __builtin_amdgcn_mfma_f32_16x16x32_bf16(av[mf], bv[nf], acc[mf][nf], 0, 0, 0);
  }
  #pragma unroll
  for (int mf = 0; mf < 3; ++mf){
    #pragma unroll
    for (int q = 0; q < 4; ++q){
      int o = 48*wv + 16*mf + 4*g + q;
      float ct = cb[o];
      #pragma unroll
      for (int nf = 0; nf < 4; ++nf){
        int col = colb + 16*nf + l15;
        float v = fmaxf(acc[mf][nf][q] + ct, 0.f);
        if (MODE){
          outf[((size_t)n*cKM + o)*cTV + col] = v;
        } else {
          int t = (col * 5243) >> 17;          // t = col / 25  (col < 1600)
          int vv = col - t * 25;
          g_pre32[(((size_t)n*cKM + o)*cT + t)*32 + vv] = f2bu(v);
        }
      }
    }
  }
}

// ---------------------------------------------------------------------------
// 5) y = pre_x @ Adyn via MFMA -> g_zt octets 0..23.
//    8 waves/block = one k-octet (8 channels); wave handles one (n,r).
//    A-frags: aligned 16B global loads from padded g_pre32.
//    B-frags: computed in registers (fast tanh); rows v>=25 exact zero.
//    Epilogue: LDS repack -> coalesced 16B [col][8] chunks of g_zt.
// ---------------------------------------------------------------------------
__global__ __launch_bounds__(512) void gm_y2(const float* __restrict__ A,
                                             const float* __restrict__ alpha){
  __shared__ ushort yst[8][cT * cV];     // 8 x 3200 B
  int tid = threadIdx.x;
  int wv = tid >> 6, lane = tid & 63, g = lane >> 4, l15 = lane & 15;
  int bid = blockIdx.x;
  int n = bid / 24, oct = bid % 24;
  int r = oct * 8 + wv;
  int k = r / cMID;
  float a0 = alpha[0];

  const float* x1p = g_x1 + ((size_t)n * cKM + r) * cV;
  const float* x2p = g_x2 + ((size_t)n * cKM + r) * cV;
  const float* Ak   = A + k * cV * cV;
  const float* adak = g_ada + ((size_t)n * cK + k) * cV * cV;

  float w0 = x2p[l15];
  int w1i = 16 + l15;
  float w1 = (w1i < cV) ? x2p[w1i] : 0.f;

  s16x8 bv0, bv1;
  #pragma unroll
  for (int j = 0; j < 8; ++j){
    int v = 8 * g + j;
    float val0 = 0.f, val1 = 0.f;
    if (v < cV){
      float xv = x1p[v];
      float e0 = __expf(2.f * (xv - w0));
      val0 = __fdividef(e0 - 1.f, e0 + 1.f) * a0 + Ak[v*cV + l15] + adak[v*cV + l15];
      if (w1i < cV){
        float e1 = __expf(2.f * (xv - w1));
        val1 = __fdividef(e1 - 1.f, e1 + 1.f) * a0 + Ak[v*cV + w1i] + adak[v*cV + w1i];
      }
    }
    bv0[j] = (short)f2bu(val0);
    bv1[j] = (short)f2bu(val1);
  }

  const ushort* pb = g_pre32 + ((size_t)n * cKM + r) * cT * 32;
  f32x4 acc[4][2];
  #pragma unroll
  for (int mf = 0; mf < 4; ++mf){
    s16x8 av = *(const s16x8*)(pb + (16*mf + l15) * 32 + 8*g);
    acc[mf][0] = __builtin_amdgcn_mfma_f32_16x16x32_bf16(av, bv0, (f32x4){0.f,0.f,0.f,0.f}, 0, 0, 0);
    acc[mf][1] = __builtin_amdgcn_mfma_f32_16x16x32_bf16(av, bv1, (f32x4){0.f,0.f,0.f,0.f}, 0, 0, 0);
  }

  // repack D -> LDS (compact [t][25])
  #pragma unroll
  for (int mf = 0; mf < 4; ++mf)
    #pragma unroll
    for (int nf = 0; nf < 2; ++nf)
      #pragma unroll
      for (int q = 0; q < 4; ++q){
        int t = 16*mf + 4*g + q, w = 16*nf + l15;
        if (w < cV) yst[wv][t * cV + w] = f2bu(acc[mf][nf][q]);
      }
  __syncthreads();
  // write phase: 512 threads emit 1600 coalesced 16B chunks [col][8ch]
  ushort* zp = g_zt + ((size_t)n * 32 + oct) * cTV * 8;
  for (int c = tid; c < cTV; c += 512){
    ushort u[8];
    #pragma unroll
    for (int w8 = 0; w8 < 8; ++w8) u[w8] = yst[w8][c];
    *(uint4*)(zp + (size_t)c * 8) = *(const uint4*)u;
  }
}

// ---------------------------------------------------------------------------
extern "C" void kernel_launch(void* const* d_in, const int* in_sizes, int n_in,
                              void* d_out, int out_size, void* d_ws, size_t ws_size,
                              hipStream_t stream){
  (void)in_sizes; (void)n_in; (void)out_size; (void)d_ws; (void)ws_size;
  const float* x      = (const float*)d_in[0];
  const float* A      = (const float*)d_in[1];
  const float* alpha  = (const float*)d_in[2];
  const float* beta   = (const float*)d_in[3];
  const float* W_pre  = (const float*)d_in[4];
  const float* b_pre  = (const float*)d_in[5];
  const float* bn_pre = (const float*)d_in[6];
  const float* W1     = (const float*)d_in[7];
  const float* b1     = (const float*)d_in[8];
  const float* W2     = (const float*)d_in[9];
  const float* b2     = (const float*)d_in[10];
  const float* W_post = (const float*)d_in[11];
  const float* b_post = (const float*)d_in[12];
  const float* bn_post= (const float*)d_in[13];
  const float* W_down = (const float*)d_in[14];
  const float* b_down = (const float*)d_in[15];
  const float* bn_down= (const float*)d_in[16];
  float* out = (float*)d_out;

  k_fold  <<<1,         256, 0, stream>>>(W_pre, b_pre, bn_pre,
                                          W_post, b_post, bn_post,
                                          W_down, b_down, bn_down);
  gm_tmp  <<<cN * cC,    64, 0, stream>>>(x);
  gm_x1x2 <<<cN * 4,    256, 0, stream>>>(W1, b1, W2, b2);
  gm_ada  <<<cN * cK,   128, 0, stream>>>(beta);
  k_xt    <<<cN * 7,    256, 0, stream>>>(x);
  gm_mm<0><<<cN * 25,   256, 0, stream>>>(nullptr);
  gm_y2   <<<cN * 24,   512, 0, stream>>>(A, alpha);
  gm_mm<1><<<cN * 25,   256, 0, stream>>>(out);
}